// Round 1
// 12511.713 us; speedup vs baseline: 1.0575x; 1.0575x over previous
//
#include <hip/hip_runtime.h>
#include <math.h>

// Problem constants (fixed by setup_inputs)
#define Bz 64
#define Tz 1024
#define Dz 512
#define Hz 256
#define Gz 1024   // 4*H
#define Kz 20

__device__ __forceinline__ float sigf(float x) { return 1.0f / (1.0f + __expf(-x)); }

// ---------------------------------------------------------------------------
// Zero-init persistent ws region: flags (2048 ints) + hbuf (65536 f) + cbuf
// (32768 f) = 100352 dwords.
// ---------------------------------------------------------------------------
__global__ __launch_bounds__(256) void init_ws(int* p) {
    int i = blockIdx.x * 256 + threadIdx.x;
    if (i < 100352) p[i] = 0;
}

// ---------------------------------------------------------------------------
// Input-gate precompute GEMM (fp32, LDS-tiled 64x64, 4x4 microtile).
// G[dir][row][sl][b] = bias[row] + sum_k W_ih[row][k] * x[b][t(dir,sl)][k]
// ---------------------------------------------------------------------------
__global__ __launch_bounds__(256) void gates_gemm(
    const float* __restrict__ x,
    const float* __restrict__ Wf, const float* __restrict__ Wb,
    const float* __restrict__ bf, const float* __restrict__ bb,
    float* __restrict__ G, int Tc, int base)
{
    __shared__ __align__(16) float As[16][68];  // [k][m], +pad
    __shared__ __align__(16) float Bs[16][68];  // [k][n]
    const int tid   = threadIdx.x;
    const int mtile = blockIdx.x;   // 16 tiles over gate rows
    const int sl    = blockIdx.y;   // chunk-local step
    const int dir   = blockIdx.z;

    const float* W    = dir ? Wb : Wf;
    const float* bias = dir ? bb : bf;
    const int s = base + sl;
    const int t = dir ? (Tz - 1 - s) : s;

    const int lr = tid >> 2;         // 0..63
    const int lk = (tid & 3) * 4;    // 0,4,8,12
    const float* Arow = W + (size_t)(mtile * 64 + lr) * Dz;
    const float* Brow = x + ((size_t)lr * Tz + t) * Dz;   // b = lr

    const int mg = tid >> 4;   // 0..15
    const int ng = tid & 15;   // 0..15
    float acc[4][4] = {};

    for (int kt = 0; kt < Dz; kt += 16) {
        float4 a4 = *(const float4*)(Arow + kt + lk);
        float4 b4 = *(const float4*)(Brow + kt + lk);
        __syncthreads();
        As[lk + 0][lr] = a4.x; As[lk + 1][lr] = a4.y;
        As[lk + 2][lr] = a4.z; As[lk + 3][lr] = a4.w;
        Bs[lk + 0][lr] = b4.x; Bs[lk + 1][lr] = b4.y;
        Bs[lk + 2][lr] = b4.z; Bs[lk + 3][lr] = b4.w;
        __syncthreads();
#pragma unroll
        for (int kk = 0; kk < 16; ++kk) {
            float4 av = *(const float4*)&As[kk][mg * 4];
            float4 bv = *(const float4*)&Bs[kk][ng * 4];
            acc[0][0] = fmaf(av.x, bv.x, acc[0][0]);
            acc[0][1] = fmaf(av.x, bv.y, acc[0][1]);
            acc[0][2] = fmaf(av.x, bv.z, acc[0][2]);
            acc[0][3] = fmaf(av.x, bv.w, acc[0][3]);
            acc[1][0] = fmaf(av.y, bv.x, acc[1][0]);
            acc[1][1] = fmaf(av.y, bv.y, acc[1][1]);
            acc[1][2] = fmaf(av.y, bv.z, acc[1][2]);
            acc[1][3] = fmaf(av.y, bv.w, acc[1][3]);
            acc[2][0] = fmaf(av.z, bv.x, acc[2][0]);
            acc[2][1] = fmaf(av.z, bv.y, acc[2][1]);
            acc[2][2] = fmaf(av.z, bv.z, acc[2][2]);
            acc[2][3] = fmaf(av.z, bv.w, acc[2][3]);
            acc[3][0] = fmaf(av.w, bv.x, acc[3][0]);
            acc[3][1] = fmaf(av.w, bv.y, acc[3][1]);
            acc[3][2] = fmaf(av.w, bv.z, acc[3][2]);
            acc[3][3] = fmaf(av.w, bv.w, acc[3][3]);
        }
    }
#pragma unroll
    for (int i = 0; i < 4; ++i) {
        int row = mtile * 64 + mg * 4 + i;
        float bvs = bias[row];
        float4 o;
        o.x = acc[i][0] + bvs; o.y = acc[i][1] + bvs;
        o.z = acc[i][2] + bvs; o.w = acc[i][3] + bvs;
        *(float4*)(G + (((size_t)dir * Gz + row) * Tc + sl) * 64 + ng * 4) = o;
    }
}

// ---------------------------------------------------------------------------
// Persistent recurrent kernel v4. 128 blocks = 2 dirs x 64 h-groups; block
// owns h-indices {4g..4g+3} (16 gate rows) x all 64 batches.
//
// v4 changes vs v3 (which was LDS-throughput-bound in the matvec):
//  * 512 threads (8 waves). Wave w = (k-quarter w&3, row-half w>>2): each
//    wave computes 8 rows x 64 k. Partials reduced through a 16KB LDS
//    buffer. This quarters the per-thread h LDS reads (64 b32, read2st64-
//    pairable) vs v3's 256.
//  * W_hh rows are loaded as WAVE-UNIFORM scalar loads (readfirstlane'd
//    wave id => compiler emits s_load_dwordx4 from K$). W never touches
//    LDS or the vector-memory pipe; FMA uses the SGPR operand slot.
//  * h staging 64KB with 2x the MLP (16 u64 per thread across 8 waves).
// Sync protocol unchanged from v3 (proven): monotone per-producer stamps,
// one coalesced poll by wave 0, parity-ring hbuf, h stores drained with
// vmcnt(0) before the stamp store; out1 store deferred past the signal.
// ---------------------------------------------------------------------------
__global__ __launch_bounds__(512, 1) void lstm_rec(
    const float* __restrict__ G,      // [2][1024][Tc][64]
    const float* __restrict__ Whf, const float* __restrict__ Whb,
    float* __restrict__ hbuf,         // [2 parity][2 dir][256][64]
    float* __restrict__ cbuf,         // [2 dir][256][64]
    float* __restrict__ out1,         // lstm_o [64][1024][512]
    int* pflag, int Tc, int base)
{
    // 64KB h + 2KB pad (pad keeps LDS > 80KB => exactly 1 block/CU)
    __shared__ __align__(16) float h_l[Hz * 64 + 512];   // [k][b]
    __shared__ __align__(16) float part_l[4][16][64];    // 16KB [kq][row][b]

    const int tid = threadIdx.x;
    const int dir = blockIdx.x >> 6;   // 0..1
    const int g   = blockIdx.x & 63;   // h-group
    const float* __restrict__ Whh = dir ? Whb : Whf;

    const int b    = tid & 63;
    // wave id as a provably-uniform value => scalar (SGPR) W loads
    const int w_id = __builtin_amdgcn_readfirstlane(tid >> 6); // 0..7
    const int kq   = w_id & 3;        // k-quarter: k in [64*kq, 64*kq+64)
    const int rh   = w_id >> 2;       // row half: local rows [8*rh, 8*rh+8)

    // Uniform row pointers for this wave's 8 gate rows, pre-offset by kq*64.
    const float* Wr[8];
#pragma unroll
    for (int i = 0; i < 8; ++i) {
        int rl = rh * 8 + i;              // local row 0..15
        int q = rl >> 2, j = rl & 3;      // gate, h-offset
        Wr[i] = Whh + (size_t)(q * Hz + g * 4 + j) * Hz + kq * 64;
    }

    const int j_ = tid >> 6;              // activation h-offset (tid<256 only)
    float c_reg = 0.0f;
    if (tid < 256) c_reg = cbuf[((size_t)dir * Hz + g * 4 + j_) * 64 + b];

    for (int sl = 0; sl < Tc; ++sl) {
        const int s = base + sl;

        // prefetch this step's input-gate contributions (activation threads)
        float gpre[4];
        if (tid < 256) {
#pragma unroll
            for (int q = 0; q < 4; ++q)
                gpre[q] = G[(((size_t)dir * Gz + q * Hz + g * 4 + j_) * Tc + sl) * 64 + b];
        }

        if (s > 0) {
            if (tid < 64) {
                const int* fp = pflag + dir * 64 + tid;
                for (;;) {
                    int v = __hip_atomic_load(fp, __ATOMIC_RELAXED,
                                              __HIP_MEMORY_SCOPE_AGENT);
                    if (__all(v >= s)) break;   // all producers done step s-1
                    __builtin_amdgcn_s_sleep(2);
                }
            }
            __syncthreads();
        }

        // stage h_s (parity s&1) into LDS: 16 coherent u64 per thread
        const unsigned long long* hsrc = (const unsigned long long*)
            (hbuf + (size_t)((s & 1) * 2 + dir) * Hz * 64);
        unsigned long long tmp[16];
#pragma unroll
        for (int jj = 0; jj < 16; ++jj)
            tmp[jj] = __hip_atomic_load(hsrc + jj * 512 + tid,
                                        __ATOMIC_RELAXED, __HIP_MEMORY_SCOPE_AGENT);
#pragma unroll
        for (int jj = 0; jj < 16; ++jj)
            ((unsigned long long*)h_l)[jj * 512 + tid] = tmp[jj];
        __syncthreads();

        // matvec: 8 rows x 64 k per wave. W from SGPRs (s_load), h from LDS
        // (lane=b, stride-64-dword pairs => ds_read2st64-friendly).
        float acc[8] = {};
        const float* hb = h_l + (size_t)(kq * 64) * 64 + b;
#pragma unroll 4
        for (int k = 0; k < 64; k += 4) {
            const float h0 = hb[(k + 0) * 64];
            const float h1 = hb[(k + 1) * 64];
            const float h2 = hb[(k + 2) * 64];
            const float h3 = hb[(k + 3) * 64];
#pragma unroll
            for (int i = 0; i < 8; ++i) {
                const float4 wv = *(const float4*)(Wr[i] + k);
                acc[i] = fmaf(h3, wv.w, fmaf(h2, wv.z,
                         fmaf(h1, wv.y, fmaf(h0, wv.x, acc[i]))));
            }
        }
#pragma unroll
        for (int i = 0; i < 8; ++i) part_l[kq][rh * 8 + i][b] = acc[i];
        __syncthreads();

        // activations: thread (j_, b), tid<256, owns h-index hx = 4g + j_
        float hv = 0.0f;
        if (tid < 256) {
            float gv[4];
#pragma unroll
            for (int q = 0; q < 4; ++q) {
                const int rl = q * 4 + j_;
                gv[q] = gpre[q] + part_l[0][rl][b] + part_l[1][rl][b]
                      + part_l[2][rl][b] + part_l[3][rl][b];
            }
            const float gi = sigf(gv[0]);
            const float gf = sigf(gv[1]);
            const float gg = tanhf(gv[2]);
            const float go = sigf(gv[3]);
            c_reg = gf * c_reg + gi * gg;
            hv = go * tanhf(c_reg);
            const int hx = g * 4 + j_;
            __hip_atomic_store(
                hbuf + ((size_t)(((s + 1) & 1) * 2 + dir) * Hz + hx) * 64 + b, hv,
                __ATOMIC_RELAXED, __HIP_MEMORY_SCOPE_AGENT);
        }

        // drain the coherent h stores, then signal (single store, no RMW)
        asm volatile("s_waitcnt vmcnt(0)" ::: "memory");
        __syncthreads();
        if (tid == 0)
            __hip_atomic_store(pflag + dir * 64 + g, s + 1,
                               __ATOMIC_RELAXED, __HIP_MEMORY_SCOPE_AGENT);

        // non-critical output store AFTER the signal (off the critical path)
        if (tid < 256) {
            const int tt = dir ? (Tz - 1 - s) : s;
            out1[((size_t)b * Tz + tt) * Dz + dir * Hz + g * 4 + j_] = hv;
        }
    }
    if (tid < 256) cbuf[((size_t)dir * Hz + g * 4 + j_) * 64 + b] = c_reg;
}

// ---------------------------------------------------------------------------
// Head: logits -> 20 smallest (softmax is monotone) -> indices + sgn_mask.
// ---------------------------------------------------------------------------
__global__ __launch_bounds__(256) void head_kernel(
    const float* __restrict__ out1, const float* __restrict__ lin_w,
    const float* __restrict__ lin_b, const unsigned char* __restrict__ mask8,
    float* __restrict__ out0, float* __restrict__ out2)
{
    __shared__ __align__(16) float lw[Dz];
    __shared__ float llog[Tz];
    __shared__ unsigned char hit[Tz];
    __shared__ float redv[4];
    __shared__ int   redi[4];

    const int tid = threadIdx.x;
    const int bb  = blockIdx.x;
    for (int i = tid; i < Dz; i += 256) lw[i] = lin_w[i];
    for (int i = tid; i < Tz; i += 256) hit[i] = 0;
    __syncthreads();

    const int w = tid >> 6, lane = tid & 63;
    const float lbv = lin_b[0];
    for (int t = w; t < Tz; t += 4) {
        const float* rp = out1 + ((size_t)bb * Tz + t) * Dz + lane * 8;
        float4 a0 = *(const float4*)rp;
        float4 a1 = *(const float4*)(rp + 4);
        const float* wp = lw + lane * 8;
        float ps = a0.x * wp[0] + a0.y * wp[1] + a0.z * wp[2] + a0.w * wp[3]
                 + a1.x * wp[4] + a1.y * wp[5] + a1.z * wp[6] + a1.w * wp[7];
        for (int o = 32; o; o >>= 1) ps += __shfl_down(ps, o);
        if (lane == 0) llog[t] = ps + lbv;
    }
    __syncthreads();

    for (int it = 0; it < Kz; ++it) {
        float bv = 3.4e38f; int bi = Tz - 1;
        for (int t = tid; t < Tz; t += 256) {
            float v = llog[t];
            if (v < bv) { bv = v; bi = t; }
        }
        for (int o = 32; o; o >>= 1) {
            float ov = __shfl_down(bv, o);
            int   oi = __shfl_down(bi, o);
            if (ov < bv || (ov == bv && oi < bi)) { bv = ov; bi = oi; }
        }
        if (lane == 0) { redv[w] = bv; redi[w] = bi; }
        __syncthreads();
        if (tid == 0) {
            for (int qq = 1; qq < 4; ++qq)
                if (redv[qq] < bv || (redv[qq] == bv && redi[qq] < bi)) { bv = redv[qq]; bi = redi[qq]; }
            out0[bb * Kz + it] = (float)bi;
            llog[bi] = 3.4e38f;
            hit[bi] = 1;
        }
        __syncthreads();
    }
    for (int t = tid; t < Tz; t += 256) {
        bool mv = mask8[(size_t)bb * Tz + t] != 0;
        out2[(size_t)bb * Tz + t] = (mv && !hit[t]) ? 1.0f : 0.0f;
    }
}

// ---------------------------------------------------------------------------
// In-place LayerNorm over last dim (512), eps=1e-5. One wave per row.
// ---------------------------------------------------------------------------
__global__ __launch_bounds__(256) void ln_kernel(
    float* __restrict__ out1, const float* __restrict__ ln_g,
    const float* __restrict__ ln_b)
{
    const int tid = threadIdx.x;
    const int w = tid >> 6, lane = tid & 63;
    const size_t row = (size_t)blockIdx.x * 4 + w;
    float* rp = out1 + row * Dz + lane * 8;
    float4 a0 = *(float4*)rp;
    float4 a1 = *(float4*)(rp + 4);
    float s  = a0.x + a0.y + a0.z + a0.w + a1.x + a1.y + a1.z + a1.w;
    float sq = a0.x*a0.x + a0.y*a0.y + a0.z*a0.z + a0.w*a0.w
             + a1.x*a1.x + a1.y*a1.y + a1.z*a1.z + a1.w*a1.w;
    for (int o = 32; o; o >>= 1) { s += __shfl_down(s, o); sq += __shfl_down(sq, o); }
    s  = __shfl(s, 0);
    sq = __shfl(sq, 0);
    const float mu  = s * (1.0f / Dz);
    const float var = sq * (1.0f / Dz) - mu * mu;
    const float rs  = rsqrtf(var + 1e-5f);
    const float* gp = ln_g + lane * 8;
    const float* bp = ln_b + lane * 8;
    a0.x = (a0.x - mu) * rs * gp[0] + bp[0];
    a0.y = (a0.y - mu) * rs * gp[1] + bp[1];
    a0.z = (a0.z - mu) * rs * gp[2] + bp[2];
    a0.w = (a0.w - mu) * rs * gp[3] + bp[3];
    a1.x = (a1.x - mu) * rs * gp[4] + bp[4];
    a1.y = (a1.y - mu) * rs * gp[5] + bp[5];
    a1.z = (a1.z - mu) * rs * gp[6] + bp[6];
    a1.w = (a1.w - mu) * rs * gp[7] + bp[7];
    *(float4*)rp = a0;
    *(float4*)(rp + 4) = a1;
}

// ---------------------------------------------------------------------------
extern "C" void kernel_launch(void* const* d_in, const int* in_sizes, int n_in,
                              void* d_out, int out_size, void* d_ws, size_t ws_size,
                              hipStream_t stream)
{
    (void)in_sizes; (void)n_in; (void)out_size;
    const float* x     = (const float*)d_in[0];
    const float* Wif   = (const float*)d_in[1];
    const float* Whf   = (const float*)d_in[2];
    const float* bf    = (const float*)d_in[3];
    const float* Wib   = (const float*)d_in[4];
    const float* Whb   = (const float*)d_in[5];
    const float* bb    = (const float*)d_in[6];
    const float* lin_w = (const float*)d_in[7];
    const float* lin_b = (const float*)d_in[8];
    const float* ln_g  = (const float*)d_in[9];
    const float* ln_b  = (const float*)d_in[10];
    const unsigned char* mask8 = (const unsigned char*)d_in[11];

    float* ws    = (float*)d_ws;
    int*   flags = (int*)d_ws;                      // 2048 ints (128 used)
    float* hbuf  = ws + 2048;                       // 65536 floats
    float* cbuf  = ws + 2048 + 65536;               // 32768 floats
    float* gates = ws + 2048 + 65536 + 32768;       // chunked gates

    const size_t fixedBytes = (size_t)(2048 + 65536 + 32768) * 4;
    const size_t avail = ws_size > fixedBytes ? ws_size - fixedBytes : 0;
    int Tc = 8;
    for (int cand = 1024; cand >= 8; cand >>= 1) {
        if ((size_t)cand * (2ull * Gz * 64 * 4) <= avail) { Tc = cand; break; }
    }

    float* out0 = (float*)d_out;
    float* out1 = out0 + (size_t)Bz * Kz;
    float* out2 = out1 + (size_t)Bz * Tz * Dz;

    init_ws<<<dim3((100352 + 255) / 256), 256, 0, stream>>>((int*)d_ws);

    const int nChunks = Tz / Tc;
    for (int c = 0; c < nChunks; ++c) {
        const int base = c * Tc;
        gates_gemm<<<dim3(16, Tc, 2), 256, 0, stream>>>(x, Wif, Wib, bf, bb, gates, Tc, base);
        lstm_rec<<<dim3(128), 512, 0, stream>>>(gates, Whf, Whb, hbuf, cbuf, out1, flags, Tc, base);
    }
    head_kernel<<<dim3(Bz), 256, 0, stream>>>(out1, lin_w, lin_b, mask8, out0, out2);
    ln_kernel<<<dim3((Bz * Tz) / 4), 256, 0, stream>>>(out1, ln_g, ln_b);
}

// Round 2
// 10508.085 us; speedup vs baseline: 1.2591x; 1.1907x over previous
//
#include <hip/hip_runtime.h>
#include <math.h>

// Problem constants (fixed by setup_inputs)
#define Bz 64
#define Tz 1024
#define Dz 512
#define Hz 256
#define Gz 1024   // 4*H
#define Kz 20
#define NBS 32    // batch slices (2 batches each)

// ws zero region: xbuf (1,048,576 u64 = 2,097,152 dwords) + hstate (32768) +
// cstate (32768)
#define WS_ZERO_DWORDS (2097152 + 32768 + 32768)

__device__ __forceinline__ float sigf(float x) { return 1.0f / (1.0f + __expf(-x)); }

__device__ __forceinline__ unsigned long long packsv(float v, unsigned st) {
    return ((unsigned long long)st << 32) | (unsigned long long)__float_as_uint(v);
}

// ---------------------------------------------------------------------------
__global__ __launch_bounds__(256) void init_ws(int* p) {
    int i = blockIdx.x * 256 + threadIdx.x;
    if (i < WS_ZERO_DWORDS) p[i] = 0;
}

// ---------------------------------------------------------------------------
// Input-gate precompute GEMM (fp32, LDS-tiled 64x64, 4x4 microtile).
// G[dir][row][sl][b] = bias[row] + sum_k W_ih[row][k] * x[b][t(dir,sl)][k]
// ---------------------------------------------------------------------------
__global__ __launch_bounds__(256) void gates_gemm(
    const float* __restrict__ x,
    const float* __restrict__ Wf, const float* __restrict__ Wb,
    const float* __restrict__ bf, const float* __restrict__ bb,
    float* __restrict__ G, int Tc, int base)
{
    __shared__ __align__(16) float As[16][68];  // [k][m], +pad
    __shared__ __align__(16) float Bs[16][68];  // [k][n]
    const int tid   = threadIdx.x;
    const int mtile = blockIdx.x;   // 16 tiles over gate rows
    const int sl    = blockIdx.y;   // chunk-local step
    const int dir   = blockIdx.z;

    const float* W    = dir ? Wb : Wf;
    const float* bias = dir ? bb : bf;
    const int s = base + sl;
    const int t = dir ? (Tz - 1 - s) : s;

    const int lr = tid >> 2;         // 0..63
    const int lk = (tid & 3) * 4;    // 0,4,8,12
    const float* Arow = W + (size_t)(mtile * 64 + lr) * Dz;
    const float* Brow = x + ((size_t)lr * Tz + t) * Dz;   // b = lr

    const int mg = tid >> 4;   // 0..15
    const int ng = tid & 15;   // 0..15
    float acc[4][4] = {};

    for (int kt = 0; kt < Dz; kt += 16) {
        float4 a4 = *(const float4*)(Arow + kt + lk);
        float4 b4 = *(const float4*)(Brow + kt + lk);
        __syncthreads();
        As[lk + 0][lr] = a4.x; As[lk + 1][lr] = a4.y;
        As[lk + 2][lr] = a4.z; As[lk + 3][lr] = a4.w;
        Bs[lk + 0][lr] = b4.x; Bs[lk + 1][lr] = b4.y;
        Bs[lk + 2][lr] = b4.z; Bs[lk + 3][lr] = b4.w;
        __syncthreads();
#pragma unroll
        for (int kk = 0; kk < 16; ++kk) {
            float4 av = *(const float4*)&As[kk][mg * 4];
            float4 bv = *(const float4*)&Bs[kk][ng * 4];
            acc[0][0] = fmaf(av.x, bv.x, acc[0][0]);
            acc[0][1] = fmaf(av.x, bv.y, acc[0][1]);
            acc[0][2] = fmaf(av.x, bv.z, acc[0][2]);
            acc[0][3] = fmaf(av.x, bv.w, acc[0][3]);
            acc[1][0] = fmaf(av.y, bv.x, acc[1][0]);
            acc[1][1] = fmaf(av.y, bv.y, acc[1][1]);
            acc[1][2] = fmaf(av.y, bv.z, acc[1][2]);
            acc[1][3] = fmaf(av.y, bv.w, acc[1][3]);
            acc[2][0] = fmaf(av.z, bv.x, acc[2][0]);
            acc[2][1] = fmaf(av.z, bv.y, acc[2][1]);
            acc[2][2] = fmaf(av.z, bv.z, acc[2][2]);
            acc[2][3] = fmaf(av.z, bv.w, acc[2][3]);
            acc[3][0] = fmaf(av.w, bv.x, acc[3][0]);
            acc[3][1] = fmaf(av.w, bv.y, acc[3][1]);
            acc[3][2] = fmaf(av.w, bv.z, acc[3][2]);
            acc[3][3] = fmaf(av.w, bv.w, acc[3][3]);
        }
    }
#pragma unroll
    for (int i = 0; i < 4; ++i) {
        int row = mtile * 64 + mg * 4 + i;
        float bvs = bias[row];
        float4 o;
        o.x = acc[i][0] + bvs; o.y = acc[i][1] + bvs;
        o.z = acc[i][2] + bvs; o.w = acc[i][3] + bvs;
        *(float4*)(G + (((size_t)dir * Gz + row) * Tc + sl) * 64 + ng * 4) = o;
    }
}

// ---------------------------------------------------------------------------
// Persistent recurrent kernel v5: register-resident W_hh, group-local sync.
//
// 256 blocks = (dir 2) x (kq 4) x (bs 32). Block owns batches {2bs, 2bs+1},
// k-range [64kq, 64kq+64), and h-range == its k-range, so h NEVER leaves the
// block (512B LDS). W_hh[all 1024 rows][its 64 k] lives in REGISTERS
// (thread t: rows 2t,2t+1 -> 128 VGPRs of W).
//
// Per step: k-loop (256 FMA/thread, h via LDS broadcast b128) -> ship partial
// gate sums: own-kq rows to LDS, peer rows to global xbuf as u64
// {f32 partial, u32 stamp=s+1} (agent scope, NO flags, NO vmcnt drain -- the
// stamp travels with the data, one visibility latency, max over 3 peers).
// Phase A: all 512 threads each spin on 3 inbox u64s, sum gates into LDS.
// Phase B: 128 threads do activations, write h to LDS + out1.
//
// Overwrite safety (2-slot parity ring, stamps monotone): peer stamp s+2
// implies that peer completed step s+1, which implies it consumed stamp-s+1
// data; so re-writing the (s&1) slot at step s+2 is safe. Same induction as
// the proven v3/v4 flag protocol, now flagless. xbuf re-zeroed each launch
// (stale stamps from a previous run would alias).
// ---------------------------------------------------------------------------
__global__ __launch_bounds__(512, 1) void lstm_rec(
    const float* __restrict__ G,      // [2][1024][Tc][64]
    const float* __restrict__ Whf, const float* __restrict__ Whb,
    unsigned long long* __restrict__ xbuf, // [2par][2dir][32bs][4dst][4src][256][2]
    float* __restrict__ hstate,       // [2][32][4][64][2]
    float* __restrict__ cstate,       // [2][32][4][64][2]
    float* __restrict__ out1,         // lstm_o [64][1024][512]
    int Tc, int base)
{
    __shared__ __align__(16) float h_l[64][2];     // current h (block-local!)
    __shared__ __align__(16) float selfP[256][2];  // own-kq partials
    __shared__ __align__(16) float gl[256][2];     // summed gates

    const int tid = threadIdx.x;
    const int blk = blockIdx.x;          // 0..255
    const int dir = blk >> 7;
    const int kq  = (blk >> 5) & 3;
    const int bs  = blk & 31;
    const float* __restrict__ Whh = dir ? Whb : Whf;

    // ---- register-resident W: rows r0=2*tid, r1=2*tid+1, k in kq range ----
    const int r0 = tid * 2;
    float w0[64], w1[64];
    {
        const float* p0 = Whh + (size_t)r0 * Hz + kq * 64;
        const float* p1 = p0 + Hz;
#pragma unroll
        for (int i = 0; i < 16; ++i) {
            float4 a = *(const float4*)(p0 + 4 * i);
            float4 c = *(const float4*)(p1 + 4 * i);
            w0[4*i+0] = a.x; w0[4*i+1] = a.y; w0[4*i+2] = a.z; w0[4*i+3] = a.w;
            w1[4*i+0] = c.x; w1[4*i+1] = c.y; w1[4*i+2] = c.z; w1[4*i+3] = c.w;
        }
    }
    const int dst  = (tid >> 5) & 3;     // destination kq of rows r0,r1
    const int rowp = (r0 >> 8) * 64 + (r0 & 63);  // row' within dst (r1 -> rowp+1)

    // phase-A identity: one (row', b) per thread
    const int arow = tid >> 1;           // 0..255
    const int ab   = tid & 1;
    const int growA = (arow >> 6) * 256 + kq * 64 + (arow & 63); // global G row
    const int bglo  = bs * 2;

    // inbox srcs (the 3 peers)
    int srcs[3];
    { int n = 0; for (int ss = 0; ss < 4; ++ss) if (ss != kq) srcs[n++] = ss; }

    // per-parity xbuf bases
    size_t ob[2], ib[2];
#pragma unroll
    for (int p = 0; p < 2; ++p) {
        ob[p] = (((((size_t)p*2 + dir)*NBS + bs)*4 + dst)*4 + kq)*512 + (size_t)rowp*2;
        ib[p] = ((((size_t)p*2 + dir)*NBS + bs)*4 + kq)*4*512 + (size_t)arow*2 + ab;
    }

    // ---- load initial h, c (zeroed by init_ws for base==0) ----
    float c_reg = 0.0f;
    {
        const size_t sb = ((size_t)(dir * NBS + bs) * 4 + kq) * 128;
        if (tid < 128) {
            h_l[tid >> 1][tid & 1] = hstate[sb + tid];
            c_reg = cstate[sb + tid];
        }
    }
    __syncthreads();

    for (int sl = 0; sl < Tc; ++sl) {
        const int s = base + sl;
        const unsigned stamp = (unsigned)(s + 1);
        const int par = s & 1;

        // G prefetch (used in phase A; issued early to hide HBM latency)
        const float gval =
            G[(((size_t)dir * Gz + growA) * Tc + sl) * 64 + (bglo + ab)];

        // ---- k-loop: 2 rows x 2 batches, W in regs, h broadcast from LDS --
        float a00 = 0.f, a01 = 0.f, a10 = 0.f, a11 = 0.f;
#pragma unroll
        for (int kk = 0; kk < 64; kk += 2) {
            const float4 hv = *(const float4*)(&h_l[kk][0]);
            a00 = fmaf(w0[kk],     hv.x, a00);
            a01 = fmaf(w0[kk],     hv.y, a01);
            a10 = fmaf(w1[kk],     hv.x, a10);
            a11 = fmaf(w1[kk],     hv.y, a11);
            a00 = fmaf(w0[kk + 1], hv.z, a00);
            a01 = fmaf(w0[kk + 1], hv.w, a01);
            a10 = fmaf(w1[kk + 1], hv.z, a10);
            a11 = fmaf(w1[kk + 1], hv.w, a11);
        }

        // ---- ship partials ----
        if (dst == kq) {
            *(float4*)&selfP[rowp][0] = make_float4(a00, a01, a10, a11);
        } else {
            unsigned long long* op = xbuf + ob[par];
            __hip_atomic_store(op + 0, packsv(a00, stamp),
                               __ATOMIC_RELAXED, __HIP_MEMORY_SCOPE_AGENT);
            __hip_atomic_store(op + 1, packsv(a01, stamp),
                               __ATOMIC_RELAXED, __HIP_MEMORY_SCOPE_AGENT);
            __hip_atomic_store(op + 2, packsv(a10, stamp),
                               __ATOMIC_RELAXED, __HIP_MEMORY_SCOPE_AGENT);
            __hip_atomic_store(op + 3, packsv(a11, stamp),
                               __ATOMIC_RELAXED, __HIP_MEMORY_SCOPE_AGENT);
        }
        __syncthreads();   // selfP visible

        // ---- phase A: gather 3 peer partials (stamp-spin), sum gates ------
        {
            const unsigned long long* ibp = xbuf + ib[par];
            const unsigned long long* i0 = ibp + (size_t)srcs[0] * 512;
            const unsigned long long* i1 = ibp + (size_t)srcs[1] * 512;
            const unsigned long long* i2 = ibp + (size_t)srcs[2] * 512;
            unsigned long long v0 = __hip_atomic_load(i0, __ATOMIC_RELAXED,
                                                      __HIP_MEMORY_SCOPE_AGENT);
            unsigned long long v1 = __hip_atomic_load(i1, __ATOMIC_RELAXED,
                                                      __HIP_MEMORY_SCOPE_AGENT);
            unsigned long long v2 = __hip_atomic_load(i2, __ATOMIC_RELAXED,
                                                      __HIP_MEMORY_SCOPE_AGENT);
            for (;;) {
                const bool o0 = (unsigned)(v0 >> 32) == stamp;
                const bool o1 = (unsigned)(v1 >> 32) == stamp;
                const bool o2 = (unsigned)(v2 >> 32) == stamp;
                if (o0 & o1 & o2) break;
                __builtin_amdgcn_s_sleep(1);
                if (!o0) v0 = __hip_atomic_load(i0, __ATOMIC_RELAXED,
                                                __HIP_MEMORY_SCOPE_AGENT);
                if (!o1) v1 = __hip_atomic_load(i1, __ATOMIC_RELAXED,
                                                __HIP_MEMORY_SCOPE_AGENT);
                if (!o2) v2 = __hip_atomic_load(i2, __ATOMIC_RELAXED,
                                                __HIP_MEMORY_SCOPE_AGENT);
            }
            gl[arow][ab] = gval + selfP[arow][ab]
                         + __uint_as_float((unsigned)v0)
                         + __uint_as_float((unsigned)v1)
                         + __uint_as_float((unsigned)v2);
        }
        __syncthreads();

        // ---- phase B: activations for own h-range (128 threads) -----------
        if (tid < 128) {
            const int bj = tid >> 1, bb2 = tid & 1;
            const float gi = sigf(gl[bj][bb2]);          // q=0 (i)
            const float gf = sigf(gl[64 + bj][bb2]);     // q=1 (f)
            const float gg = tanhf(gl[128 + bj][bb2]);   // q=2 (g)
            const float go = sigf(gl[192 + bj][bb2]);    // q=3 (o)
            c_reg = gf * c_reg + gi * gg;
            const float hv = go * tanhf(c_reg);
            h_l[bj][bb2] = hv;
            const int tt = dir ? (Tz - 1 - s) : s;
            out1[((size_t)(bglo + bb2) * Tz + tt) * Dz + dir * Hz + kq * 64 + bj] = hv;
        }
        __syncthreads();   // h_l ready for next step's k-loop
    }

    // persist state for chunked relaunch
    if (tid < 128) {
        const size_t sb = ((size_t)(dir * NBS + bs) * 4 + kq) * 128;
        hstate[sb + tid] = h_l[tid >> 1][tid & 1];
        cstate[sb + tid] = c_reg;
    }
}

// ---------------------------------------------------------------------------
// Head: logits -> 20 smallest (softmax is monotone) -> indices + sgn_mask.
// ---------------------------------------------------------------------------
__global__ __launch_bounds__(256) void head_kernel(
    const float* __restrict__ out1, const float* __restrict__ lin_w,
    const float* __restrict__ lin_b, const unsigned char* __restrict__ mask8,
    float* __restrict__ out0, float* __restrict__ out2)
{
    __shared__ __align__(16) float lw[Dz];
    __shared__ float llog[Tz];
    __shared__ unsigned char hit[Tz];
    __shared__ float redv[4];
    __shared__ int   redi[4];

    const int tid = threadIdx.x;
    const int bb  = blockIdx.x;
    for (int i = tid; i < Dz; i += 256) lw[i] = lin_w[i];
    for (int i = tid; i < Tz; i += 256) hit[i] = 0;
    __syncthreads();

    const int w = tid >> 6, lane = tid & 63;
    const float lbv = lin_b[0];
    for (int t = w; t < Tz; t += 4) {
        const float* rp = out1 + ((size_t)bb * Tz + t) * Dz + lane * 8;
        float4 a0 = *(const float4*)rp;
        float4 a1 = *(const float4*)(rp + 4);
        const float* wp = lw + lane * 8;
        float ps = a0.x * wp[0] + a0.y * wp[1] + a0.z * wp[2] + a0.w * wp[3]
                 + a1.x * wp[4] + a1.y * wp[5] + a1.z * wp[6] + a1.w * wp[7];
        for (int o = 32; o; o >>= 1) ps += __shfl_down(ps, o);
        if (lane == 0) llog[t] = ps + lbv;
    }
    __syncthreads();

    for (int it = 0; it < Kz; ++it) {
        float bv = 3.4e38f; int bi = Tz - 1;
        for (int t = tid; t < Tz; t += 256) {
            float v = llog[t];
            if (v < bv) { bv = v; bi = t; }
        }
        for (int o = 32; o; o >>= 1) {
            float ov = __shfl_down(bv, o);
            int   oi = __shfl_down(bi, o);
            if (ov < bv || (ov == bv && oi < bi)) { bv = ov; bi = oi; }
        }
        if (lane == 0) { redv[w] = bv; redi[w] = bi; }
        __syncthreads();
        if (tid == 0) {
            for (int qq = 1; qq < 4; ++qq)
                if (redv[qq] < bv || (redv[qq] == bv && redi[qq] < bi)) { bv = redv[qq]; bi = redi[qq]; }
            out0[bb * Kz + it] = (float)bi;
            llog[bi] = 3.4e38f;
            hit[bi] = 1;
        }
        __syncthreads();
    }
    for (int t = tid; t < Tz; t += 256) {
        bool mv = mask8[(size_t)bb * Tz + t] != 0;
        out2[(size_t)bb * Tz + t] = (mv && !hit[t]) ? 1.0f : 0.0f;
    }
}

// ---------------------------------------------------------------------------
// In-place LayerNorm over last dim (512), eps=1e-5. One wave per row.
// ---------------------------------------------------------------------------
__global__ __launch_bounds__(256) void ln_kernel(
    float* __restrict__ out1, const float* __restrict__ ln_g,
    const float* __restrict__ ln_b)
{
    const int tid = threadIdx.x;
    const int w = tid >> 6, lane = tid & 63;
    const size_t row = (size_t)blockIdx.x * 4 + w;
    float* rp = out1 + row * Dz + lane * 8;
    float4 a0 = *(float4*)rp;
    float4 a1 = *(float4*)(rp + 4);
    float s  = a0.x + a0.y + a0.z + a0.w + a1.x + a1.y + a1.z + a1.w;
    float sq = a0.x*a0.x + a0.y*a0.y + a0.z*a0.z + a0.w*a0.w
             + a1.x*a1.x + a1.y*a1.y + a1.z*a1.z + a1.w*a1.w;
    for (int o = 32; o; o >>= 1) { s += __shfl_down(s, o); sq += __shfl_down(sq, o); }
    s  = __shfl(s, 0);
    sq = __shfl(sq, 0);
    const float mu  = s * (1.0f / Dz);
    const float var = sq * (1.0f / Dz) - mu * mu;
    const float rs  = rsqrtf(var + 1e-5f);
    const float* gp = ln_g + lane * 8;
    const float* bp = ln_b + lane * 8;
    a0.x = (a0.x - mu) * rs * gp[0] + bp[0];
    a0.y = (a0.y - mu) * rs * gp[1] + bp[1];
    a0.z = (a0.z - mu) * rs * gp[2] + bp[2];
    a0.w = (a0.w - mu) * rs * gp[3] + bp[3];
    a1.x = (a1.x - mu) * rs * gp[4] + bp[4];
    a1.y = (a1.y - mu) * rs * gp[5] + bp[5];
    a1.z = (a1.z - mu) * rs * gp[6] + bp[6];
    a1.w = (a1.w - mu) * rs * gp[7] + bp[7];
    *(float4*)rp = a0;
    *(float4*)(rp + 4) = a1;
}

// ---------------------------------------------------------------------------
extern "C" void kernel_launch(void* const* d_in, const int* in_sizes, int n_in,
                              void* d_out, int out_size, void* d_ws, size_t ws_size,
                              hipStream_t stream)
{
    (void)in_sizes; (void)n_in; (void)out_size;
    const float* x     = (const float*)d_in[0];
    const float* Wif   = (const float*)d_in[1];
    const float* Whf   = (const float*)d_in[2];
    const float* bf    = (const float*)d_in[3];
    const float* Wib   = (const float*)d_in[4];
    const float* Whb   = (const float*)d_in[5];
    const float* bb    = (const float*)d_in[6];
    const float* lin_w = (const float*)d_in[7];
    const float* lin_b = (const float*)d_in[8];
    const float* ln_g  = (const float*)d_in[9];
    const float* ln_b  = (const float*)d_in[10];
    const unsigned char* mask8 = (const unsigned char*)d_in[11];

    float* ws = (float*)d_ws;
    unsigned long long* xbuf = (unsigned long long*)ws;   // 1,048,576 u64 (8MB)
    float* hstate = ws + 2097152;                         // 32768 f
    float* cstate = hstate + 32768;                       // 32768 f
    float* gates  = cstate + 32768;                       // chunked gates

    const size_t fixedBytes = (size_t)(2097152 + 65536) * 4;
    const size_t avail = ws_size > fixedBytes ? ws_size - fixedBytes : 0;
    int Tc = 8;
    for (int cand = 1024; cand >= 8; cand >>= 1) {
        if ((size_t)cand * (2ull * Gz * 64 * 4) <= avail) { Tc = cand; break; }
    }

    float* out0 = (float*)d_out;
    float* out1 = out0 + (size_t)Bz * Kz;
    float* out2 = out1 + (size_t)Bz * Tz * Dz;

    init_ws<<<dim3((WS_ZERO_DWORDS + 255) / 256), 256, 0, stream>>>((int*)d_ws);

    const int nChunks = Tz / Tc;
    for (int c = 0; c < nChunks; ++c) {
        const int base = c * Tc;
        gates_gemm<<<dim3(16, Tc, 2), 256, 0, stream>>>(x, Wif, Wib, bf, bb, gates, Tc, base);
        lstm_rec<<<dim3(256), 512, 0, stream>>>(gates, Whf, Whb, xbuf, hstate, cstate,
                                                out1, Tc, base);
    }
    head_kernel<<<dim3(Bz), 256, 0, stream>>>(out1, lin_w, lin_b, mask8, out0, out2);
    ln_kernel<<<dim3((Bz * Tz) / 4), 256, 0, stream>>>(out1, ln_g, ln_b);
}